// Round 1
// baseline (6713.467 us; speedup 1.0000x reference)
//
#include <hip/hip_runtime.h>

#define F_IN 512
#define H1   8
#define D1   8
#define C1   64   // H1*D1
#define C2   40

__device__ __forceinline__ float leaky02(float x) { return x > 0.f ? x : 0.2f * x; }

// ---------------------------------------------------------------------------
// GEMM1: h1 = x @ W1  (N x 512) @ (512 x 64), fused alpha_src/alpha_dst epilogue.
// Block 256 threads = 4 lane-groups of 64; each group handles nodes g and g+4
// (8 nodes per block, 2-node register blocking). W1 staged in LDS in K-chunks.
// ---------------------------------------------------------------------------
__global__ __launch_bounds__(256) void gemm1_kernel(
    const float* __restrict__ x, const float* __restrict__ W1,
    const float* __restrict__ a_src, const float* __restrict__ a_dst,
    float* __restrict__ h1, float* __restrict__ as1, float* __restrict__ ad1,
    int N)
{
    __shared__ float xs[8][F_IN];   // 16 KB
    __shared__ float Ws[64][C1];    // 16 KB
    const int tid = threadIdx.x;
    const int g   = tid >> 6;       // 0..3
    const int c   = tid & 63;       // output column
    const int n0  = blockIdx.x * 8;

    // stage 8 x-rows: 8*512 floats = 1024 float4, coalesced
    {
        const float4* xg = (const float4*)(x + (size_t)n0 * F_IN);
        float4* xl = (float4*)&xs[0][0];
        for (int i = tid; i < 1024; i += 256) xl[i] = xg[i];
    }

    float accA = 0.f, accB = 0.f;
    for (int kb = 0; kb < F_IN; kb += 64) {
        __syncthreads();   // protect xs (first iter) / previous Ws reads
        {
            const float4* wg = (const float4*)(W1 + (size_t)kb * C1);
            float4* wl = (float4*)&Ws[0][0];
            for (int i = tid; i < 1024; i += 256) wl[i] = wg[i];
        }
        __syncthreads();
        #pragma unroll
        for (int kk = 0; kk < 64; ++kk) {
            float w = Ws[kk][c];
            accA += xs[g][kb + kk] * w;       // broadcast read (wave-uniform)
            accB += xs[g + 4][kb + kk] * w;
        }
    }

    const int nA = n0 + g, nB = n0 + 4 + g;
    h1[(size_t)nA * C1 + c] = accA;
    h1[(size_t)nB * C1 + c] = accB;

    // alpha_{s,d}[n,h] = sum_d h1[n,h,d] * att[h,d]; c = h*8+d -> reduce over 8 lanes
    float sA = accA * a_src[c], dA = accA * a_dst[c];
    float sB = accB * a_src[c], dB = accB * a_dst[c];
    #pragma unroll
    for (int m = 1; m < 8; m <<= 1) {
        sA += __shfl_xor(sA, m); dA += __shfl_xor(dA, m);
        sB += __shfl_xor(sB, m); dB += __shfl_xor(dB, m);
    }
    if ((c & 7) == 0) {
        const int h = c >> 3;
        as1[nA * H1 + h] = sA; ad1[nA * H1 + h] = dA;
        as1[nB * H1 + h] = sB; ad1[nB * H1 + h] = dB;
    }
}

// ---------------------------------------------------------------------------
// Layer-1 edge aggregation: thread per (edge, head).
// No max-subtraction: value ranges (|e| < ~3) make exp() safe; softmax is
// shift-invariant so result is mathematically identical.
// ---------------------------------------------------------------------------
__global__ __launch_bounds__(256) void edge_agg1_kernel(
    const int* __restrict__ ei, const float* __restrict__ h1,
    const float* __restrict__ as1, const float* __restrict__ ad1,
    float* __restrict__ num1, float* __restrict__ den1, int E)
{
    int t = blockIdx.x * 256 + threadIdx.x;
    int e = t >> 3;
    if (e >= E) return;
    int h = t & 7;
    int src = ei[e], dst = ei[E + e];
    float a  = as1[src * H1 + h] + ad1[dst * H1 + h];
    float ex = __expf(leaky02(a));
    atomicAdd(&den1[dst * H1 + h], ex);
    const float4* hs = (const float4*)(h1 + (size_t)src * C1 + h * D1);
    float4 v0 = hs[0], v1 = hs[1];
    float* nd = num1 + (size_t)dst * C1 + h * D1;
    atomicAdd(nd + 0, ex * v0.x); atomicAdd(nd + 1, ex * v0.y);
    atomicAdd(nd + 2, ex * v0.z); atomicAdd(nd + 3, ex * v0.w);
    atomicAdd(nd + 4, ex * v1.x); atomicAdd(nd + 5, ex * v1.y);
    atomicAdd(nd + 6, ex * v1.z); atomicAdd(nd + 7, ex * v1.w);
}

// ---------------------------------------------------------------------------
// Layer-1 finish: add self-loop contribution, normalize, +b1, ELU.
// Writes h1f in place into num1. Thread per (node, channel).
// ---------------------------------------------------------------------------
__global__ __launch_bounds__(256) void finish1_kernel(
    const float* __restrict__ h1, const float* __restrict__ as1,
    const float* __restrict__ ad1, const float* __restrict__ b1,
    float* __restrict__ num1, const float* __restrict__ den1, int N)
{
    int t = blockIdx.x * 256 + threadIdx.x;
    if (t >= N * C1) return;
    int n = t >> 6, c = t & 63, h = c >> 3;
    float ex  = __expf(leaky02(as1[n * H1 + h] + ad1[n * H1 + h]));
    float agg = (num1[t] + ex * h1[t]) / (den1[n * H1 + h] + ex);
    float v   = agg + b1[c];
    num1[t]   = v > 0.f ? v : __expf(v) - 1.f;   // ELU
}

// ---------------------------------------------------------------------------
// GEMM2: h2 = h1f @ W2  (N x 64) @ (64 x 40), fused alpha2 epilogue.
// Block 320 threads = 8 nodes x 40 columns.
// ---------------------------------------------------------------------------
__global__ __launch_bounds__(320) void gemm2_kernel(
    const float* __restrict__ h1f, const float* __restrict__ W2,
    const float* __restrict__ a_src2, const float* __restrict__ a_dst2,
    float* __restrict__ h2, float* __restrict__ as2, float* __restrict__ ad2,
    int N)
{
    __shared__ float hs[8][C1];          // 2 KB
    __shared__ float W2s[C1 * C2];       // 10.24 KB
    __shared__ float redS[8][C2], redD[8][C2];
    const int tid = threadIdx.x;
    const int n0  = blockIdx.x * 8;
    for (int i = tid; i < 8 * C1; i += 320) hs[i >> 6][i & 63] = h1f[(size_t)n0 * C1 + i];
    for (int i = tid; i < C1 * C2; i += 320) W2s[i] = W2[i];
    __syncthreads();
    const int g = tid / C2, c = tid % C2;
    float acc = 0.f;
    #pragma unroll
    for (int k = 0; k < C1; ++k) acc += hs[g][k] * W2s[k * C2 + c];
    const int n = n0 + g;
    h2[(size_t)n * C2 + c] = acc;
    redS[g][c] = acc * a_src2[c];
    redD[g][c] = acc * a_dst2[c];
    __syncthreads();
    if (c == 0) {
        float s = 0.f, d = 0.f;
        for (int j = 0; j < C2; ++j) { s += redS[g][j]; d += redD[g][j]; }
        as2[n] = s; ad2[n] = d;
    }
}

// ---------------------------------------------------------------------------
// Layer-2 edge aggregation: thread per edge, 40-wide vectorized gather + atomics.
// ---------------------------------------------------------------------------
__global__ __launch_bounds__(256) void edge_agg2_kernel(
    const int* __restrict__ ei, const float* __restrict__ h2,
    const float* __restrict__ as2, const float* __restrict__ ad2,
    float* __restrict__ num2, float* __restrict__ den2, int E)
{
    int e = blockIdx.x * 256 + threadIdx.x;
    if (e >= E) return;
    int src = ei[e], dst = ei[E + e];
    float ex = __expf(leaky02(as2[src] + ad2[dst]));
    atomicAdd(&den2[dst], ex);
    const float4* hp = (const float4*)(h2 + (size_t)src * C2);
    float* np = num2 + (size_t)dst * C2;
    #pragma unroll
    for (int q = 0; q < 10; ++q) {
        float4 v = hp[q];
        atomicAdd(np + q * 4 + 0, ex * v.x);
        atomicAdd(np + q * 4 + 1, ex * v.y);
        atomicAdd(np + q * 4 + 2, ex * v.z);
        atomicAdd(np + q * 4 + 3, ex * v.w);
    }
}

// ---------------------------------------------------------------------------
// Layer-2 finish: self-loop + normalize + b2 + log_softmax over 40 classes.
// One 64-lane wave per node (40 active), shuffle reductions.
// ---------------------------------------------------------------------------
__global__ __launch_bounds__(256) void finish2_kernel(
    const float* __restrict__ h2, const float* __restrict__ as2,
    const float* __restrict__ ad2, const float* __restrict__ b2,
    const float* __restrict__ num2, const float* __restrict__ den2,
    float* __restrict__ out, int N)
{
    int t = blockIdx.x * 256 + threadIdx.x;
    int n = t >> 6, lane = t & 63;
    if (n >= N) return;
    float ex = __expf(leaky02(as2[n] + ad2[n]));
    float v = -1e30f;
    if (lane < C2) {
        v = (num2[(size_t)n * C2 + lane] + ex * h2[(size_t)n * C2 + lane])
            / (den2[n] + ex) + b2[lane];
    }
    float m = v;
    #pragma unroll
    for (int s = 1; s < 64; s <<= 1) m = fmaxf(m, __shfl_xor(m, s));
    float e2 = (lane < C2) ? __expf(v - m) : 0.f;
    #pragma unroll
    for (int s = 1; s < 64; s <<= 1) e2 += __shfl_xor(e2, s);
    float lse = __logf(e2);
    if (lane < C2) out[(size_t)n * C2 + lane] = v - m - lse;
}

// ---------------------------------------------------------------------------
extern "C" void kernel_launch(void* const* d_in, const int* in_sizes, int n_in,
                              void* d_out, int out_size, void* d_ws, size_t ws_size,
                              hipStream_t stream)
{
    const float* x    = (const float*)d_in[0];
    const int*   ei   = (const int*)  d_in[1];
    const float* W1   = (const float*)d_in[2];
    const float* as1w = (const float*)d_in[3];
    const float* ad1w = (const float*)d_in[4];
    const float* b1   = (const float*)d_in[5];
    const float* W2   = (const float*)d_in[6];
    const float* as2w = (const float*)d_in[7];
    const float* ad2w = (const float*)d_in[8];
    const float* b2   = (const float*)d_in[9];

    const int N = in_sizes[0] / F_IN;   // 100000
    const int E = in_sizes[1] / 2;      // 1600000

    float* ws = (float*)d_ws;
    size_t o = 0;
    float* num1 = ws + o; o += (size_t)N * C1;   // layer1 numerator -> h1f in place
    float* den1 = ws + o; o += (size_t)N * H1;
    float* num2 = ws + o; o += (size_t)N * C2;
    float* den2 = ws + o; o += (size_t)N;
    const size_t zero_bytes = o * sizeof(float);
    float* h1  = ws + o; o += (size_t)N * C1;
    float* as1 = ws + o; o += (size_t)N * H1;
    float* ad1 = ws + o; o += (size_t)N * H1;
    float* h2  = ws + o; o += (size_t)N * C2;
    float* as2 = ws + o; o += (size_t)N;
    float* ad2 = ws + o; o += (size_t)N;

    hipMemsetAsync(num1, 0, zero_bytes, stream);

    gemm1_kernel<<<N / 8, 256, 0, stream>>>(x, W1, as1w, ad1w, h1, as1, ad1, N);
    edge_agg1_kernel<<<(E * 8 + 255) / 256, 256, 0, stream>>>(ei, h1, as1, ad1, num1, den1, E);
    finish1_kernel<<<(N * C1 + 255) / 256, 256, 0, stream>>>(h1, as1, ad1, b1, num1, den1, N);
    gemm2_kernel<<<N / 8, 320, 0, stream>>>(num1, W2, as2w, ad2w, h2, as2, ad2, N);
    edge_agg2_kernel<<<(E + 255) / 256, 256, 0, stream>>>(ei, h2, as2, ad2, num2, den2, E);
    finish2_kernel<<<(N * 64 + 255) / 256, 256, 0, stream>>>(h2, as2, ad2, b2, num2, den2,
                                                             (float*)d_out, N);
}

// Round 2
// 906.114 us; speedup vs baseline: 7.4091x; 7.4091x over previous
//
#include <hip/hip_runtime.h>

#define F_IN 512
#define H1   8
#define D1   8
#define C1   64   // H1*D1
#define C2   40

__device__ __forceinline__ float leaky02(float x) { return x > 0.f ? x : 0.2f * x; }

// ---------------------------------------------------------------------------
// GEMM1: h1 = x @ W1  (N x 512) @ (512 x 64), fused alpha_src/alpha_dst epilogue.
// ---------------------------------------------------------------------------
__global__ __launch_bounds__(256) void gemm1_kernel(
    const float* __restrict__ x, const float* __restrict__ W1,
    const float* __restrict__ a_src, const float* __restrict__ a_dst,
    float* __restrict__ h1, float* __restrict__ as1, float* __restrict__ ad1,
    int N)
{
    __shared__ float xs[8][F_IN];   // 16 KB
    __shared__ float Ws[64][C1];    // 16 KB
    const int tid = threadIdx.x;
    const int g   = tid >> 6;       // 0..3
    const int c   = tid & 63;       // output column
    const int n0  = blockIdx.x * 8;

    {
        const float4* xg = (const float4*)(x + (size_t)n0 * F_IN);
        float4* xl = (float4*)&xs[0][0];
        for (int i = tid; i < 1024; i += 256) xl[i] = xg[i];
    }

    float accA = 0.f, accB = 0.f;
    for (int kb = 0; kb < F_IN; kb += 64) {
        __syncthreads();
        {
            const float4* wg = (const float4*)(W1 + (size_t)kb * C1);
            float4* wl = (float4*)&Ws[0][0];
            for (int i = tid; i < 1024; i += 256) wl[i] = wg[i];
        }
        __syncthreads();
        #pragma unroll
        for (int kk = 0; kk < 64; ++kk) {
            float w = Ws[kk][c];
            accA += xs[g][kb + kk] * w;
            accB += xs[g + 4][kb + kk] * w;
        }
    }

    const int nA = n0 + g, nB = n0 + 4 + g;
    h1[(size_t)nA * C1 + c] = accA;
    h1[(size_t)nB * C1 + c] = accB;

    float sA = accA * a_src[c], dA = accA * a_dst[c];
    float sB = accB * a_src[c], dB = accB * a_dst[c];
    #pragma unroll
    for (int m = 1; m < 8; m <<= 1) {
        sA += __shfl_xor(sA, m); dA += __shfl_xor(dA, m);
        sB += __shfl_xor(sB, m); dB += __shfl_xor(dB, m);
    }
    if ((c & 7) == 0) {
        const int h = c >> 3;
        as1[nA * H1 + h] = sA; ad1[nA * H1 + h] = dA;
        as1[nB * H1 + h] = sB; ad1[nB * H1 + h] = dB;
    }
}

// ---------------------------------------------------------------------------
// CSR build: count -> scan(3 kernels) -> scatter. Reused by both layers.
// ---------------------------------------------------------------------------
__global__ __launch_bounds__(256) void count_kernel(
    const int* __restrict__ ei, int* __restrict__ deg, int E)
{
    int e = blockIdx.x * 256 + threadIdx.x;
    if (e >= E) return;
    atomicAdd(&deg[ei[E + e]], 1);
}

__global__ __launch_bounds__(512) void scan1_kernel(
    const int* __restrict__ deg, int* __restrict__ excl,
    int* __restrict__ bsum, int N)
{
    __shared__ int sA[512], sB[512];
    const int t = threadIdx.x;
    const int i = blockIdx.x * 512 + t;
    int v = (i < N) ? deg[i] : 0;
    sA[t] = v; __syncthreads();
    int* pin = sA; int* pout = sB;
    #pragma unroll
    for (int off = 1; off < 512; off <<= 1) {
        pout[t] = pin[t] + ((t >= off) ? pin[t - off] : 0);
        __syncthreads();
        int* tmp = pin; pin = pout; pout = tmp;
    }
    if (i < N) excl[i] = pin[t] - v;
    if (t == 511) bsum[blockIdx.x] = pin[511];
}

__global__ __launch_bounds__(256) void scan2_kernel(
    int* __restrict__ bsum, int* __restrict__ bsumo, int NB)
{
    __shared__ int sA[256], sB[256];
    const int t = threadIdx.x;
    int v = (t < NB) ? bsum[t] : 0;
    sA[t] = v; __syncthreads();
    int* pin = sA; int* pout = sB;
    #pragma unroll
    for (int off = 1; off < 256; off <<= 1) {
        pout[t] = pin[t] + ((t >= off) ? pin[t - off] : 0);
        __syncthreads();
        int* tmp = pin; pin = pout; pout = tmp;
    }
    if (t < NB) bsumo[t] = pin[t] - v;   // exclusive
}

__global__ __launch_bounds__(512) void scan3_kernel(
    const int* __restrict__ excl, const int* __restrict__ bsumo,
    int* __restrict__ rowptr, int* __restrict__ cursor, int N, int E)
{
    const int i = blockIdx.x * 512 + threadIdx.x;
    if (i < N) {
        int r = excl[i] + bsumo[blockIdx.x];
        rowptr[i] = r;
        cursor[i] = r;
    }
    if (i == 0) rowptr[N] = E;
}

__global__ __launch_bounds__(256) void scatter_kernel(
    const int* __restrict__ ei, int* __restrict__ cursor,
    int* __restrict__ esrc, int E)
{
    int e = blockIdx.x * 256 + threadIdx.x;
    if (e >= E) return;
    int src = ei[e], dst = ei[E + e];
    int pos = atomicAdd(&cursor[dst], 1);
    esrc[pos] = src;
}

// ---------------------------------------------------------------------------
// Layer-1 aggregation + finish (self-loop, normalize, +b1, ELU), fused.
// One 64-lane wave per dst node; lane = channel, head = lane>>3.
// den is accumulated redundantly per-lane (identical within an 8-lane head).
// ---------------------------------------------------------------------------
__global__ __launch_bounds__(256) void agg1_kernel(
    const int* __restrict__ rowptr, const int* __restrict__ esrc,
    const float* __restrict__ h1, const float* __restrict__ as1,
    const float* __restrict__ ad1, const float* __restrict__ b1,
    float* __restrict__ h1f, int N)
{
    const int n = blockIdx.x * 4 + (threadIdx.x >> 6);
    if (n >= N) return;
    const int lane = threadIdx.x & 63;
    const int h = lane >> 3;
    const float adh = ad1[n * H1 + h];

    float acc = 0.f, den = 0.f;
    const int beg = rowptr[n], end = rowptr[n + 1];
    for (int i = beg; i < end; ++i) {
        int src = esrc[i];
        float ex = __expf(leaky02(as1[src * H1 + h] + adh));
        acc += ex * h1[(size_t)src * C1 + lane];
        den += ex;
    }
    // self loop
    {
        float ex = __expf(leaky02(as1[n * H1 + h] + adh));
        acc += ex * h1[(size_t)n * C1 + lane];
        den += ex;
    }
    float v = acc / den + b1[lane];
    h1f[(size_t)n * C1 + lane] = v > 0.f ? v : __expf(v) - 1.f;   // ELU
}

// ---------------------------------------------------------------------------
// GEMM2: h2 = h1f @ W2  (N x 64) @ (64 x 40), fused alpha2 epilogue.
// ---------------------------------------------------------------------------
__global__ __launch_bounds__(320) void gemm2_kernel(
    const float* __restrict__ h1f, const float* __restrict__ W2,
    const float* __restrict__ a_src2, const float* __restrict__ a_dst2,
    float* __restrict__ h2, float* __restrict__ as2, float* __restrict__ ad2,
    int N)
{
    __shared__ float hs[8][C1];
    __shared__ float W2s[C1 * C2];
    __shared__ float redS[8][C2], redD[8][C2];
    const int tid = threadIdx.x;
    const int n0  = blockIdx.x * 8;
    for (int i = tid; i < 8 * C1; i += 320) hs[i >> 6][i & 63] = h1f[(size_t)n0 * C1 + i];
    for (int i = tid; i < C1 * C2; i += 320) W2s[i] = W2[i];
    __syncthreads();
    const int g = tid / C2, c = tid % C2;
    float acc = 0.f;
    #pragma unroll
    for (int k = 0; k < C1; ++k) acc += hs[g][k] * W2s[k * C2 + c];
    const int n = n0 + g;
    h2[(size_t)n * C2 + c] = acc;
    redS[g][c] = acc * a_src2[c];
    redD[g][c] = acc * a_dst2[c];
    __syncthreads();
    if (c == 0) {
        float s = 0.f, d = 0.f;
        for (int j = 0; j < C2; ++j) { s += redS[g][j]; d += redD[g][j]; }
        as2[n] = s; ad2[n] = d;
    }
}

// ---------------------------------------------------------------------------
// Layer-2 aggregation + finish + log_softmax, fused.
// One wave per dst node; lanes 0..39 = classes.
// ---------------------------------------------------------------------------
__global__ __launch_bounds__(256) void agg2_kernel(
    const int* __restrict__ rowptr, const int* __restrict__ esrc,
    const float* __restrict__ h2, const float* __restrict__ as2,
    const float* __restrict__ ad2, const float* __restrict__ b2,
    float* __restrict__ out, int N)
{
    const int n = blockIdx.x * 4 + (threadIdx.x >> 6);
    if (n >= N) return;
    const int lane = threadIdx.x & 63;
    const float adn = ad2[n];

    float acc = 0.f, den = 0.f;
    const int beg = rowptr[n], end = rowptr[n + 1];
    for (int i = beg; i < end; ++i) {
        int src = esrc[i];
        float ex = __expf(leaky02(as2[src] + adn));
        if (lane < C2) acc += ex * h2[(size_t)src * C2 + lane];
        den += ex;
    }
    {
        float ex = __expf(leaky02(as2[n] + adn));
        if (lane < C2) acc += ex * h2[(size_t)n * C2 + lane];
        den += ex;
    }
    float v = (lane < C2) ? (acc / den + b2[lane]) : -1e30f;
    float m = v;
    #pragma unroll
    for (int s = 1; s < 64; s <<= 1) m = fmaxf(m, __shfl_xor(m, s));
    float e2 = (lane < C2) ? __expf(v - m) : 0.f;
    #pragma unroll
    for (int s = 1; s < 64; s <<= 1) e2 += __shfl_xor(e2, s);
    float lse = __logf(e2);
    if (lane < C2) out[(size_t)n * C2 + lane] = v - m - lse;
}

// ---------------------------------------------------------------------------
extern "C" void kernel_launch(void* const* d_in, const int* in_sizes, int n_in,
                              void* d_out, int out_size, void* d_ws, size_t ws_size,
                              hipStream_t stream)
{
    const float* x    = (const float*)d_in[0];
    const int*   ei   = (const int*)  d_in[1];
    const float* W1   = (const float*)d_in[2];
    const float* as1w = (const float*)d_in[3];
    const float* ad1w = (const float*)d_in[4];
    const float* b1   = (const float*)d_in[5];
    const float* W2   = (const float*)d_in[6];
    const float* as2w = (const float*)d_in[7];
    const float* ad2w = (const float*)d_in[8];
    const float* b2   = (const float*)d_in[9];

    const int N = in_sizes[0] / F_IN;   // 100000
    const int E = in_sizes[1] / 2;      // 1600000

    char* base = (char*)d_ws;
    auto carve = [&](size_t bytes) -> void* {
        void* p = (void*)base;
        base += (bytes + 255) & ~(size_t)255;
        return p;
    };
    float* h1     = (float*)carve((size_t)N * C1 * 4);
    float* h1f    = (float*)carve((size_t)N * C1 * 4);
    float* as1    = (float*)carve((size_t)N * H1 * 4);
    float* ad1    = (float*)carve((size_t)N * H1 * 4);
    float* h2     = (float*)carve((size_t)N * C2 * 4);
    float* as2    = (float*)carve((size_t)N * 4);
    float* ad2    = (float*)carve((size_t)N * 4);
    int*   deg    = (int*)carve((size_t)N * 4);
    int*   excl   = (int*)carve((size_t)N * 4);
    int*   rowptr = (int*)carve((size_t)(N + 1) * 4);
    int*   cursor = (int*)carve((size_t)N * 4);
    int*   esrc   = (int*)carve((size_t)E * 4);
    int*   bsum   = (int*)carve(256 * 4);
    int*   bsumo  = (int*)carve(256 * 4);

    const int NB = (N + 511) / 512;   // 196 scan blocks

    hipMemsetAsync(deg, 0, (size_t)N * 4, stream);

    // CSR build (independent of gemm1; shared by both layers)
    count_kernel<<<(E + 255) / 256, 256, 0, stream>>>(ei, deg, E);
    scan1_kernel<<<NB, 512, 0, stream>>>(deg, excl, bsum, N);
    scan2_kernel<<<1, 256, 0, stream>>>(bsum, bsumo, NB);
    scan3_kernel<<<NB, 512, 0, stream>>>(excl, bsumo, rowptr, cursor, N, E);
    scatter_kernel<<<(E + 255) / 256, 256, 0, stream>>>(ei, cursor, esrc, E);

    gemm1_kernel<<<N / 8, 256, 0, stream>>>(x, W1, as1w, ad1w, h1, as1, ad1, N);
    agg1_kernel<<<(N + 3) / 4, 256, 0, stream>>>(rowptr, esrc, h1, as1, ad1, b1, h1f, N);
    gemm2_kernel<<<N / 8, 320, 0, stream>>>(h1f, W2, as2w, ad2w, h2, as2, ad2, N);
    agg2_kernel<<<(N + 3) / 4, 256, 0, stream>>>(rowptr, esrc, h2, as2, ad2, b2,
                                                 (float*)d_out, N);
}

// Round 3
// 744.597 us; speedup vs baseline: 9.0162x; 1.2169x over previous
//
#include <hip/hip_runtime.h>

#define F_IN 512
#define H1   8
#define D1   8
#define C1   64   // H1*D1
#define C2   40

__device__ __forceinline__ float leaky02(float x) { return x > 0.f ? x : 0.2f * x; }

// ---------------------------------------------------------------------------
// GEMM1 v2: h1 = x @ W1 (N x 512)@(512 x 64), fused alpha epilogue.
// Tile 128 nodes x 64 cols, BK=32. 256 threads; per-thread 8 nodes x 4 cols
// (32 acc). x staged TRANSPOSED in LDS so inner loop = 3 ds_read_b128 per
// 32 FMAs (VALU-bound, was 1:1 ds_read_b32:FMA -> LDS-pipe-bound).
// xsT padded to 132 floats/row: keeps 16B alignment, writes <=4-way conflict.
// ---------------------------------------------------------------------------
__global__ __launch_bounds__(256, 4) void gemm1_kernel(
    const float* __restrict__ x, const float* __restrict__ W1,
    const float* __restrict__ a_src, const float* __restrict__ a_dst,
    float* __restrict__ h1, float* __restrict__ as1, float* __restrict__ ad1,
    int N)
{
    __shared__ float xsT[32][132];   // 16.9 KB (transposed x chunk)
    __shared__ float Ws[32][64];     // 8 KB
    const int tid = threadIdx.x;
    const int cg  = tid & 15;        // col group: cols cg*4..cg*4+3
    const int ng  = tid >> 4;        // node group: nodes ng*8..ng*8+7
    const int n0  = blockIdx.x * 128;

    float a_s[4], a_d[4];
    #pragma unroll
    for (int j = 0; j < 4; ++j) { a_s[j] = a_src[cg * 4 + j]; a_d[j] = a_dst[cg * 4 + j]; }

    float acc[8][4];
    #pragma unroll
    for (int i = 0; i < 8; ++i)
        #pragma unroll
        for (int j = 0; j < 4; ++j) acc[i][j] = 0.f;

    const int xrow0 = tid >> 3;      // + 32*r
    const int xq    = tid & 7;       // k-quad within chunk

    for (int kb = 0; kb < F_IN; kb += 32) {
        __syncthreads();
        // stage x^T: 128 rows x 32 k, coalesced global float4, transposed write
        #pragma unroll
        for (int r = 0; r < 4; ++r) {
            const int nl = xrow0 + 32 * r;
            int n = n0 + nl; if (n > N - 1) n = N - 1;   // clamp tail
            float4 v = *(const float4*)&x[(size_t)n * F_IN + kb + xq * 4];
            xsT[xq * 4 + 0][nl] = v.x;
            xsT[xq * 4 + 1][nl] = v.y;
            xsT[xq * 4 + 2][nl] = v.z;
            xsT[xq * 4 + 3][nl] = v.w;
        }
        // stage W chunk: 32 x 64 floats, linear copy
        #pragma unroll
        for (int r = 0; r < 2; ++r) {
            const int i2 = tid + 256 * r;
            *(float4*)&Ws[i2 >> 4][(i2 & 15) * 4] =
                *(const float4*)&W1[(size_t)kb * C1 + (size_t)i2 * 4];
        }
        __syncthreads();
        #pragma unroll 8
        for (int kk = 0; kk < 32; ++kk) {
            float4 xa = *(float4*)&xsT[kk][ng * 8];
            float4 xb = *(float4*)&xsT[kk][ng * 8 + 4];
            float4 wv = *(float4*)&Ws[kk][cg * 4];
            const float xv[8] = {xa.x, xa.y, xa.z, xa.w, xb.x, xb.y, xb.z, xb.w};
            const float wj[4] = {wv.x, wv.y, wv.z, wv.w};
            #pragma unroll
            for (int i = 0; i < 8; ++i)
                #pragma unroll
                for (int j = 0; j < 4; ++j)
                    acc[i][j] += xv[i] * wj[j];
        }
    }

    // epilogue: h1 store + alpha reductions (pair cg,cg^1 covers one head)
    #pragma unroll
    for (int i = 0; i < 8; ++i) {
        const int n = n0 + ng * 8 + i;
        float s = acc[i][0] * a_s[0] + acc[i][1] * a_s[1]
                + acc[i][2] * a_s[2] + acc[i][3] * a_s[3];
        float d = acc[i][0] * a_d[0] + acc[i][1] * a_d[1]
                + acc[i][2] * a_d[2] + acc[i][3] * a_d[3];
        s += __shfl_xor(s, 1);
        d += __shfl_xor(d, 1);
        if (n < N) {
            *(float4*)&h1[(size_t)n * C1 + cg * 4] =
                make_float4(acc[i][0], acc[i][1], acc[i][2], acc[i][3]);
            if (!(cg & 1)) {
                as1[n * H1 + (cg >> 1)] = s;
                ad1[n * H1 + (cg >> 1)] = d;
            }
        }
    }
}

// ---------------------------------------------------------------------------
// CSR build: count -> scan(3 kernels) -> scatter. Reused by both layers.
// ---------------------------------------------------------------------------
__global__ __launch_bounds__(256) void count_kernel(
    const int* __restrict__ ei, int* __restrict__ deg, int E)
{
    int e = blockIdx.x * 256 + threadIdx.x;
    if (e >= E) return;
    atomicAdd(&deg[ei[E + e]], 1);
}

__global__ __launch_bounds__(512) void scan1_kernel(
    const int* __restrict__ deg, int* __restrict__ excl,
    int* __restrict__ bsum, int N)
{
    __shared__ int sA[512], sB[512];
    const int t = threadIdx.x;
    const int i = blockIdx.x * 512 + t;
    int v = (i < N) ? deg[i] : 0;
    sA[t] = v; __syncthreads();
    int* pin = sA; int* pout = sB;
    #pragma unroll
    for (int off = 1; off < 512; off <<= 1) {
        pout[t] = pin[t] + ((t >= off) ? pin[t - off] : 0);
        __syncthreads();
        int* tmp = pin; pin = pout; pout = tmp;
    }
    if (i < N) excl[i] = pin[t] - v;
    if (t == 511) bsum[blockIdx.x] = pin[511];
}

__global__ __launch_bounds__(256) void scan2_kernel(
    int* __restrict__ bsum, int* __restrict__ bsumo, int NB)
{
    __shared__ int sA[256], sB[256];
    const int t = threadIdx.x;
    int v = (t < NB) ? bsum[t] : 0;
    sA[t] = v; __syncthreads();
    int* pin = sA; int* pout = sB;
    #pragma unroll
    for (int off = 1; off < 256; off <<= 1) {
        pout[t] = pin[t] + ((t >= off) ? pin[t - off] : 0);
        __syncthreads();
        int* tmp = pin; pin = pout; pout = tmp;
    }
    if (t < NB) bsumo[t] = pin[t] - v;   // exclusive
}

__global__ __launch_bounds__(512) void scan3_kernel(
    const int* __restrict__ excl, const int* __restrict__ bsumo,
    int* __restrict__ rowptr, int* __restrict__ cursor, int N, int E)
{
    const int i = blockIdx.x * 512 + threadIdx.x;
    if (i < N) {
        int r = excl[i] + bsumo[blockIdx.x];
        rowptr[i] = r;
        cursor[i] = r;
    }
    if (i == 0) rowptr[N] = E;
}

__global__ __launch_bounds__(256) void scatter_kernel(
    const int* __restrict__ ei, int* __restrict__ cursor,
    int* __restrict__ esrc, int E)
{
    int e = blockIdx.x * 256 + threadIdx.x;
    if (e >= E) return;
    int src = ei[e], dst = ei[E + e];
    int pos = atomicAdd(&cursor[dst], 1);
    esrc[pos] = src;
}

// ---------------------------------------------------------------------------
// Layer-1 aggregation + finish (self-loop, normalize, +b1, ELU), fused.
// One 64-lane wave per dst node; lane = channel, head = lane>>3.
// ---------------------------------------------------------------------------
__global__ __launch_bounds__(256) void agg1_kernel(
    const int* __restrict__ rowptr, const int* __restrict__ esrc,
    const float* __restrict__ h1, const float* __restrict__ as1,
    const float* __restrict__ ad1, const float* __restrict__ b1,
    float* __restrict__ h1f, int N)
{
    const int n = blockIdx.x * 4 + (threadIdx.x >> 6);
    if (n >= N) return;
    const int lane = threadIdx.x & 63;
    const int h = lane >> 3;
    const float adh = ad1[n * H1 + h];

    float acc = 0.f, den = 0.f;
    const int beg = rowptr[n], end = rowptr[n + 1];
    for (int i = beg; i < end; ++i) {
        int src = esrc[i];
        float ex = __expf(leaky02(as1[src * H1 + h] + adh));
        acc += ex * h1[(size_t)src * C1 + lane];
        den += ex;
    }
    {
        float ex = __expf(leaky02(as1[n * H1 + h] + adh));
        acc += ex * h1[(size_t)n * C1 + lane];
        den += ex;
    }
    float v = acc / den + b1[lane];
    h1f[(size_t)n * C1 + lane] = v > 0.f ? v : __expf(v) - 1.f;   // ELU
}

// ---------------------------------------------------------------------------
// GEMM2: h2 = h1f @ W2  (N x 64) @ (64 x 40), fused alpha2 epilogue.
// ---------------------------------------------------------------------------
__global__ __launch_bounds__(320) void gemm2_kernel(
    const float* __restrict__ h1f, const float* __restrict__ W2,
    const float* __restrict__ a_src2, const float* __restrict__ a_dst2,
    float* __restrict__ h2, float* __restrict__ as2, float* __restrict__ ad2,
    int N)
{
    __shared__ float hs[8][C1];
    __shared__ float W2s[C1 * C2];
    __shared__ float redS[8][C2], redD[8][C2];
    const int tid = threadIdx.x;
    const int n0  = blockIdx.x * 8;
    for (int i = tid; i < 8 * C1; i += 320) hs[i >> 6][i & 63] = h1f[(size_t)n0 * C1 + i];
    for (int i = tid; i < C1 * C2; i += 320) W2s[i] = W2[i];
    __syncthreads();
    const int g = tid / C2, c = tid % C2;
    float acc = 0.f;
    #pragma unroll
    for (int k = 0; k < C1; ++k) acc += hs[g][k] * W2s[k * C2 + c];
    const int n = n0 + g;
    h2[(size_t)n * C2 + c] = acc;
    redS[g][c] = acc * a_src2[c];
    redD[g][c] = acc * a_dst2[c];
    __syncthreads();
    if (c == 0) {
        float s = 0.f, d = 0.f;
        for (int j = 0; j < C2; ++j) { s += redS[g][j]; d += redD[g][j]; }
        as2[n] = s; ad2[n] = d;
    }
}

// ---------------------------------------------------------------------------
// Layer-2 aggregation + finish + log_softmax, fused.
// ---------------------------------------------------------------------------
__global__ __launch_bounds__(256) void agg2_kernel(
    const int* __restrict__ rowptr, const int* __restrict__ esrc,
    const float* __restrict__ h2, const float* __restrict__ as2,
    const float* __restrict__ ad2, const float* __restrict__ b2,
    float* __restrict__ out, int N)
{
    const int n = blockIdx.x * 4 + (threadIdx.x >> 6);
    if (n >= N) return;
    const int lane = threadIdx.x & 63;
    const float adn = ad2[n];

    float acc = 0.f, den = 0.f;
    const int beg = rowptr[n], end = rowptr[n + 1];
    for (int i = beg; i < end; ++i) {
        int src = esrc[i];
        float ex = __expf(leaky02(as2[src] + adn));
        if (lane < C2) acc += ex * h2[(size_t)src * C2 + lane];
        den += ex;
    }
    {
        float ex = __expf(leaky02(as2[n] + adn));
        if (lane < C2) acc += ex * h2[(size_t)n * C2 + lane];
        den += ex;
    }
    float v = (lane < C2) ? (acc / den + b2[lane]) : -1e30f;
    float m = v;
    #pragma unroll
    for (int s = 1; s < 64; s <<= 1) m = fmaxf(m, __shfl_xor(m, s));
    float e2 = (lane < C2) ? __expf(v - m) : 0.f;
    #pragma unroll
    for (int s = 1; s < 64; s <<= 1) e2 += __shfl_xor(e2, s);
    float lse = __logf(e2);
    if (lane < C2) out[(size_t)n * C2 + lane] = v - m - lse;
}

// ---------------------------------------------------------------------------
extern "C" void kernel_launch(void* const* d_in, const int* in_sizes, int n_in,
                              void* d_out, int out_size, void* d_ws, size_t ws_size,
                              hipStream_t stream)
{
    const float* x    = (const float*)d_in[0];
    const int*   ei   = (const int*)  d_in[1];
    const float* W1   = (const float*)d_in[2];
    const float* as1w = (const float*)d_in[3];
    const float* ad1w = (const float*)d_in[4];
    const float* b1   = (const float*)d_in[5];
    const float* W2   = (const float*)d_in[6];
    const float* as2w = (const float*)d_in[7];
    const float* ad2w = (const float*)d_in[8];
    const float* b2   = (const float*)d_in[9];

    const int N = in_sizes[0] / F_IN;   // 100000
    const int E = in_sizes[1] / 2;      // 1600000

    char* base = (char*)d_ws;
    auto carve = [&](size_t bytes) -> void* {
        void* p = (void*)base;
        base += (bytes + 255) & ~(size_t)255;
        return p;
    };
    float* h1     = (float*)carve((size_t)N * C1 * 4);
    float* h1f    = (float*)carve((size_t)N * C1 * 4);
    float* as1    = (float*)carve((size_t)N * H1 * 4);
    float* ad1    = (float*)carve((size_t)N * H1 * 4);
    float* h2     = (float*)carve((size_t)N * C2 * 4);
    float* as2    = (float*)carve((size_t)N * 4);
    float* ad2    = (float*)carve((size_t)N * 4);
    int*   deg    = (int*)carve((size_t)N * 4);
    int*   excl   = (int*)carve((size_t)N * 4);
    int*   rowptr = (int*)carve((size_t)(N + 1) * 4);
    int*   cursor = (int*)carve((size_t)N * 4);
    int*   esrc   = (int*)carve((size_t)E * 4);
    int*   bsum   = (int*)carve(256 * 4);
    int*   bsumo  = (int*)carve(256 * 4);

    const int NB = (N + 511) / 512;

    hipMemsetAsync(deg, 0, (size_t)N * 4, stream);

    count_kernel<<<(E + 255) / 256, 256, 0, stream>>>(ei, deg, E);
    scan1_kernel<<<NB, 512, 0, stream>>>(deg, excl, bsum, N);
    scan2_kernel<<<1, 256, 0, stream>>>(bsum, bsumo, NB);
    scan3_kernel<<<NB, 512, 0, stream>>>(excl, bsumo, rowptr, cursor, N, E);
    scatter_kernel<<<(E + 255) / 256, 256, 0, stream>>>(ei, cursor, esrc, E);

    gemm1_kernel<<<(N + 127) / 128, 256, 0, stream>>>(x, W1, as1w, ad1w, h1, as1, ad1, N);
    agg1_kernel<<<(N + 3) / 4, 256, 0, stream>>>(rowptr, esrc, h1, as1, ad1, b1, h1f, N);
    gemm2_kernel<<<N / 8, 320, 0, stream>>>(h1f, W2, as2w, ad2w, h2, as2, ad2, N);
    agg2_kernel<<<(N + 3) / 4, 256, 0, stream>>>(rowptr, esrc, h2, as2, ad2, b2,
                                                 (float*)d_out, N);
}

// Round 4
// 519.259 us; speedup vs baseline: 12.9289x; 1.4340x over previous
//
#include <hip/hip_runtime.h>

#define F_IN 512
#define H1   8
#define D1   8
#define C1   64   // H1*D1
#define C2   40

__device__ __forceinline__ float leaky02(float x) { return x > 0.f ? x : 0.2f * x; }

// ---------------------------------------------------------------------------
// GEMM1 v2: h1 = x @ W1 (N x 512)@(512 x 64), fused alpha epilogue.
// Tile 128 nodes x 64 cols, BK=32; per-thread 8x4 register tile.
// ---------------------------------------------------------------------------
__global__ __launch_bounds__(256, 4) void gemm1_kernel(
    const float* __restrict__ x, const float* __restrict__ W1,
    const float* __restrict__ a_src, const float* __restrict__ a_dst,
    float* __restrict__ h1, float* __restrict__ as1, float* __restrict__ ad1,
    int N)
{
    __shared__ float xsT[32][132];   // 16.9 KB (transposed x chunk)
    __shared__ float Ws[32][64];     // 8 KB
    const int tid = threadIdx.x;
    const int cg  = tid & 15;
    const int ng  = tid >> 4;
    const int n0  = blockIdx.x * 128;

    float a_s[4], a_d[4];
    #pragma unroll
    for (int j = 0; j < 4; ++j) { a_s[j] = a_src[cg * 4 + j]; a_d[j] = a_dst[cg * 4 + j]; }

    float acc[8][4];
    #pragma unroll
    for (int i = 0; i < 8; ++i)
        #pragma unroll
        for (int j = 0; j < 4; ++j) acc[i][j] = 0.f;

    const int xrow0 = tid >> 3;
    const int xq    = tid & 7;

    for (int kb = 0; kb < F_IN; kb += 32) {
        __syncthreads();
        #pragma unroll
        for (int r = 0; r < 4; ++r) {
            const int nl = xrow0 + 32 * r;
            int n = n0 + nl; if (n > N - 1) n = N - 1;
            float4 v = *(const float4*)&x[(size_t)n * F_IN + kb + xq * 4];
            xsT[xq * 4 + 0][nl] = v.x;
            xsT[xq * 4 + 1][nl] = v.y;
            xsT[xq * 4 + 2][nl] = v.z;
            xsT[xq * 4 + 3][nl] = v.w;
        }
        #pragma unroll
        for (int r = 0; r < 2; ++r) {
            const int i2 = tid + 256 * r;
            *(float4*)&Ws[i2 >> 4][(i2 & 15) * 4] =
                *(const float4*)&W1[(size_t)kb * C1 + (size_t)i2 * 4];
        }
        __syncthreads();
        #pragma unroll 8
        for (int kk = 0; kk < 32; ++kk) {
            float4 xa = *(float4*)&xsT[kk][ng * 8];
            float4 xb = *(float4*)&xsT[kk][ng * 8 + 4];
            float4 wv = *(float4*)&Ws[kk][cg * 4];
            const float xv[8] = {xa.x, xa.y, xa.z, xa.w, xb.x, xb.y, xb.z, xb.w};
            const float wj[4] = {wv.x, wv.y, wv.z, wv.w};
            #pragma unroll
            for (int i = 0; i < 8; ++i)
                #pragma unroll
                for (int j = 0; j < 4; ++j)
                    acc[i][j] += xv[i] * wj[j];
        }
    }

    #pragma unroll
    for (int i = 0; i < 8; ++i) {
        const int n = n0 + ng * 8 + i;
        float s = acc[i][0] * a_s[0] + acc[i][1] * a_s[1]
                + acc[i][2] * a_s[2] + acc[i][3] * a_s[3];
        float d = acc[i][0] * a_d[0] + acc[i][1] * a_d[1]
                + acc[i][2] * a_d[2] + acc[i][3] * a_d[3];
        s += __shfl_xor(s, 1);
        d += __shfl_xor(d, 1);
        if (n < N) {
            *(float4*)&h1[(size_t)n * C1 + cg * 4] =
                make_float4(acc[i][0], acc[i][1], acc[i][2], acc[i][3]);
            if (!(cg & 1)) {
                as1[n * H1 + (cg >> 1)] = s;
                ad1[n * H1 + (cg >> 1)] = d;
            }
        }
    }
}

// ---------------------------------------------------------------------------
// CSR build: count -> scan(3 kernels) -> scatter.
// ---------------------------------------------------------------------------
__global__ __launch_bounds__(256) void count_kernel(
    const int* __restrict__ ei, int* __restrict__ deg, int E)
{
    int e = blockIdx.x * 256 + threadIdx.x;
    if (e >= E) return;
    atomicAdd(&deg[ei[E + e]], 1);
}

__global__ __launch_bounds__(512) void scan1_kernel(
    const int* __restrict__ deg, int* __restrict__ excl,
    int* __restrict__ bsum, int N)
{
    __shared__ int sA[512], sB[512];
    const int t = threadIdx.x;
    const int i = blockIdx.x * 512 + t;
    int v = (i < N) ? deg[i] : 0;
    sA[t] = v; __syncthreads();
    int* pin = sA; int* pout = sB;
    #pragma unroll
    for (int off = 1; off < 512; off <<= 1) {
        pout[t] = pin[t] + ((t >= off) ? pin[t - off] : 0);
        __syncthreads();
        int* tmp = pin; pin = pout; pout = tmp;
    }
    if (i < N) excl[i] = pin[t] - v;
    if (t == 511) bsum[blockIdx.x] = pin[511];
}

__global__ __launch_bounds__(256) void scan2_kernel(
    int* __restrict__ bsum, int* __restrict__ bsumo, int NB)
{
    __shared__ int sA[256], sB[256];
    const int t = threadIdx.x;
    int v = (t < NB) ? bsum[t] : 0;
    sA[t] = v; __syncthreads();
    int* pin = sA; int* pout = sB;
    #pragma unroll
    for (int off = 1; off < 256; off <<= 1) {
        pout[t] = pin[t] + ((t >= off) ? pin[t - off] : 0);
        __syncthreads();
        int* tmp = pin; pin = pout; pout = tmp;
    }
    if (t < NB) bsumo[t] = pin[t] - v;
}

__global__ __launch_bounds__(512) void scan3_kernel(
    const int* __restrict__ excl, const int* __restrict__ bsumo,
    int* __restrict__ rowptr, int* __restrict__ cursor, int N, int E)
{
    const int i = blockIdx.x * 512 + threadIdx.x;
    if (i < N) {
        int r = excl[i] + bsumo[blockIdx.x];
        rowptr[i] = r;
        cursor[i] = r;
    }
    if (i == 0) rowptr[N] = E;
}

__global__ __launch_bounds__(256) void scatter_kernel(
    const int* __restrict__ ei, int* __restrict__ cursor,
    int* __restrict__ esrc, int E)
{
    int e = blockIdx.x * 256 + threadIdx.x;
    if (e >= E) return;
    int src = ei[e], dst = ei[E + e];
    int pos = atomicAdd(&cursor[dst], 1);
    esrc[pos] = src;
}

// ---------------------------------------------------------------------------
// Layer-1 aggregation + finish, fused. One wave per dst node.
// 4-edge software pipeline: 4 esrc loads -> 8 independent gathers -> consume.
// ---------------------------------------------------------------------------
__global__ __launch_bounds__(256) void agg1_kernel(
    const int* __restrict__ rowptr, const int* __restrict__ esrc,
    const float* __restrict__ h1, const float* __restrict__ as1,
    const float* __restrict__ ad1, const float* __restrict__ b1,
    float* __restrict__ h1f, int N)
{
    const int n = blockIdx.x * 4 + (threadIdx.x >> 6);
    if (n >= N) return;
    const int lane = threadIdx.x & 63;
    const int h = lane >> 3;
    const float adh = ad1[n * H1 + h];

    float acc = 0.f, den = 0.f;
    int i = rowptr[n];
    const int end = rowptr[n + 1];
    for (; i + 4 <= end; i += 4) {
        const int s0 = esrc[i], s1 = esrc[i + 1], s2 = esrc[i + 2], s3 = esrc[i + 3];
        const float v0 = h1[(size_t)s0 * C1 + lane];
        const float v1 = h1[(size_t)s1 * C1 + lane];
        const float v2 = h1[(size_t)s2 * C1 + lane];
        const float v3 = h1[(size_t)s3 * C1 + lane];
        const float a0 = as1[s0 * H1 + h], a1 = as1[s1 * H1 + h];
        const float a2 = as1[s2 * H1 + h], a3 = as1[s3 * H1 + h];
        const float e0 = __expf(leaky02(a0 + adh));
        const float e1 = __expf(leaky02(a1 + adh));
        const float e2 = __expf(leaky02(a2 + adh));
        const float e3 = __expf(leaky02(a3 + adh));
        acc += e0 * v0; acc += e1 * v1; acc += e2 * v2; acc += e3 * v3;
        den += (e0 + e1) + (e2 + e3);
    }
    for (; i < end; ++i) {
        const int src = esrc[i];
        const float v  = h1[(size_t)src * C1 + lane];
        const float ex = __expf(leaky02(as1[src * H1 + h] + adh));
        acc += ex * v;
        den += ex;
    }
    {   // self loop
        const float ex = __expf(leaky02(as1[n * H1 + h] + adh));
        acc += ex * h1[(size_t)n * C1 + lane];
        den += ex;
    }
    float v = acc / den + b1[lane];
    h1f[(size_t)n * C1 + lane] = v > 0.f ? v : __expf(v) - 1.f;   // ELU
}

// ---------------------------------------------------------------------------
// GEMM2: h2 = h1f @ W2  (N x 64) @ (64 x 40), fused alpha2 epilogue.
// ---------------------------------------------------------------------------
__global__ __launch_bounds__(320) void gemm2_kernel(
    const float* __restrict__ h1f, const float* __restrict__ W2,
    const float* __restrict__ a_src2, const float* __restrict__ a_dst2,
    float* __restrict__ h2, float* __restrict__ as2, float* __restrict__ ad2,
    int N)
{
    __shared__ float hs[8][C1];
    __shared__ float W2s[C1 * C2];
    __shared__ float redS[8][C2], redD[8][C2];
    const int tid = threadIdx.x;
    const int n0  = blockIdx.x * 8;
    for (int i = tid; i < 8 * C1; i += 320) hs[i >> 6][i & 63] = h1f[(size_t)n0 * C1 + i];
    for (int i = tid; i < C1 * C2; i += 320) W2s[i] = W2[i];
    __syncthreads();
    const int g = tid / C2, c = tid % C2;
    float acc = 0.f;
    #pragma unroll
    for (int k = 0; k < C1; ++k) acc += hs[g][k] * W2s[k * C2 + c];
    const int n = n0 + g;
    h2[(size_t)n * C2 + c] = acc;
    redS[g][c] = acc * a_src2[c];
    redD[g][c] = acc * a_dst2[c];
    __syncthreads();
    if (c == 0) {
        float s = 0.f, d = 0.f;
        for (int j = 0; j < C2; ++j) { s += redS[g][j]; d += redD[g][j]; }
        as2[n] = s; ad2[n] = d;
    }
}

// ---------------------------------------------------------------------------
// Layer-2 aggregation + finish + log_softmax, fused. 4-edge pipeline.
// ---------------------------------------------------------------------------
__global__ __launch_bounds__(256) void agg2_kernel(
    const int* __restrict__ rowptr, const int* __restrict__ esrc,
    const float* __restrict__ h2, const float* __restrict__ as2,
    const float* __restrict__ ad2, const float* __restrict__ b2,
    float* __restrict__ out, int N)
{
    const int n = blockIdx.x * 4 + (threadIdx.x >> 6);
    if (n >= N) return;
    const int lane = threadIdx.x & 63;
    const float adn = ad2[n];

    float acc = 0.f, den = 0.f;
    int i = rowptr[n];
    const int end = rowptr[n + 1];
    for (; i + 4 <= end; i += 4) {
        const int s0 = esrc[i], s1 = esrc[i + 1], s2 = esrc[i + 2], s3 = esrc[i + 3];
        float v0 = 0.f, v1 = 0.f, v2 = 0.f, v3 = 0.f;
        if (lane < C2) {
            v0 = h2[(size_t)s0 * C2 + lane];
            v1 = h2[(size_t)s1 * C2 + lane];
            v2 = h2[(size_t)s2 * C2 + lane];
            v3 = h2[(size_t)s3 * C2 + lane];
        }
        const float a0 = as2[s0], a1 = as2[s1], a2 = as2[s2], a3 = as2[s3];
        const float e0 = __expf(leaky02(a0 + adn));
        const float e1 = __expf(leaky02(a1 + adn));
        const float e2 = __expf(leaky02(a2 + adn));
        const float e3 = __expf(leaky02(a3 + adn));
        acc += e0 * v0; acc += e1 * v1; acc += e2 * v2; acc += e3 * v3;
        den += (e0 + e1) + (e2 + e3);
    }
    for (; i < end; ++i) {
        const int src = esrc[i];
        float v = 0.f;
        if (lane < C2) v = h2[(size_t)src * C2 + lane];
        const float ex = __expf(leaky02(as2[src] + adn));
        acc += ex * v;
        den += ex;
    }
    {   // self loop
        const float ex = __expf(leaky02(as2[n] + adn));
        if (lane < C2) acc += ex * h2[(size_t)n * C2 + lane];
        den += ex;
    }
    float v = (lane < C2) ? (acc / den + b2[lane]) : -1e30f;
    float m = v;
    #pragma unroll
    for (int s = 1; s < 64; s <<= 1) m = fmaxf(m, __shfl_xor(m, s));
    float e2x = (lane < C2) ? __expf(v - m) : 0.f;
    #pragma unroll
    for (int s = 1; s < 64; s <<= 1) e2x += __shfl_xor(e2x, s);
    float lse = __logf(e2x);
    if (lane < C2) out[(size_t)n * C2 + lane] = v - m - lse;
}

// ---------------------------------------------------------------------------
extern "C" void kernel_launch(void* const* d_in, const int* in_sizes, int n_in,
                              void* d_out, int out_size, void* d_ws, size_t ws_size,
                              hipStream_t stream)
{
    const float* x    = (const float*)d_in[0];
    const int*   ei   = (const int*)  d_in[1];
    const float* W1   = (const float*)d_in[2];
    const float* as1w = (const float*)d_in[3];
    const float* ad1w = (const float*)d_in[4];
    const float* b1   = (const float*)d_in[5];
    const float* W2   = (const float*)d_in[6];
    const float* as2w = (const float*)d_in[7];
    const float* ad2w = (const float*)d_in[8];
    const float* b2   = (const float*)d_in[9];

    const int N = in_sizes[0] / F_IN;   // 100000
    const int E = in_sizes[1] / 2;      // 1600000

    char* base = (char*)d_ws;
    auto carve = [&](size_t bytes) -> void* {
        void* p = (void*)base;
        base += (bytes + 255) & ~(size_t)255;
        return p;
    };
    float* h1     = (float*)carve((size_t)N * C1 * 4);
    float* h1f    = (float*)carve((size_t)N * C1 * 4);
    float* as1    = (float*)carve((size_t)N * H1 * 4);
    float* ad1    = (float*)carve((size_t)N * H1 * 4);
    float* h2     = (float*)carve((size_t)N * C2 * 4);
    float* as2    = (float*)carve((size_t)N * 4);
    float* ad2    = (float*)carve((size_t)N * 4);
    int*   deg    = (int*)carve((size_t)N * 4);
    int*   excl   = (int*)carve((size_t)N * 4);
    int*   rowptr = (int*)carve((size_t)(N + 1) * 4);
    int*   cursor = (int*)carve((size_t)N * 4);
    int*   esrc   = (int*)carve((size_t)E * 4);
    int*   bsum   = (int*)carve(256 * 4);
    int*   bsumo  = (int*)carve(256 * 4);

    const int NB = (N + 511) / 512;

    hipMemsetAsync(deg, 0, (size_t)N * 4, stream);

    count_kernel<<<(E + 255) / 256, 256, 0, stream>>>(ei, deg, E);
    scan1_kernel<<<NB, 512, 0, stream>>>(deg, excl, bsum, N);
    scan2_kernel<<<1, 256, 0, stream>>>(bsum, bsumo, NB);
    scan3_kernel<<<NB, 512, 0, stream>>>(excl, bsumo, rowptr, cursor, N, E);
    scatter_kernel<<<(E + 255) / 256, 256, 0, stream>>>(ei, cursor, esrc, E);

    gemm1_kernel<<<(N + 127) / 128, 256, 0, stream>>>(x, W1, as1w, ad1w, h1, as1, ad1, N);
    agg1_kernel<<<(N + 3) / 4, 256, 0, stream>>>(rowptr, esrc, h1, as1, ad1, b1, h1f, N);
    gemm2_kernel<<<N / 8, 320, 0, stream>>>(h1f, W2, as2w, ad2w, h2, as2, ad2, N);
    agg2_kernel<<<(N + 3) / 4, 256, 0, stream>>>(rowptr, esrc, h2, as2, ad2, b2,
                                                 (float*)d_out, N);
}